// Round 3
// baseline (152.674 us; speedup 1.0000x reference)
//
#include <hip/hip_runtime.h>

// ConditionalDense: out[b,u] = sum_d x[b,d]*kernel[cls[b],d,u] + bias[cls[b],u]
// B=2048, D=512, U=512, C=100, all float32.
// R2: fused single-block sort; main kernel DF=8 D-split + double-buffered
// W prefetch (4 float4 in flight per wave). Partials via f32 atomicAdd.

constexpr int C_CLS   = 100;
constexpr int B_N     = 2048;
constexpr int D_DIM   = 512;
constexpr int U_DIM   = 512;
constexpr int S_CHUNK = 8;      // samples per chunk
constexpr int MAX_CHUNKS = 360; // >= worst-case sum(ceil(n_c/8)) = 256+100=356
constexpr int TU      = 256;    // u-columns per block (64 threads x 4 u each)
constexpr int DF      = 8;      // D-split factor
constexpr int DS      = D_DIM / DF;  // 64 d-rows per block

// ---------------- fused sort kernel (single block, 1024 threads) ----------------

__global__ void k_sort(const int* __restrict__ cls, int* __restrict__ order,
                       int* __restrict__ total_chunks, int* __restrict__ chunk_cls,
                       int* __restrict__ chunk_start, int* __restrict__ chunk_len) {
    __shared__ int s_cnt[128], s_off[128], s_chk[128], s_cur[128], s_base[128];
    int tid = threadIdx.x;
    if (tid < 128) s_cnt[tid] = 0;
    __syncthreads();
    for (int i = tid; i < B_N; i += 1024) atomicAdd(&s_cnt[cls[i]], 1);
    __syncthreads();
    int cnt = 0, nch = 0;
    if (tid < 128) {
        cnt = (tid < C_CLS) ? s_cnt[tid] : 0;
        nch = (cnt + S_CHUNK - 1) / S_CHUNK;
        s_off[tid] = cnt; s_chk[tid] = nch;
    }
    __syncthreads();
    for (int st = 1; st < 128; st <<= 1) {   // Hillis-Steele inclusive scan
        int a = 0, b = 0;
        if (tid >= st && tid < 128) { a = s_off[tid - st]; b = s_chk[tid - st]; }
        __syncthreads();
        if (tid < 128) { s_off[tid] += a; s_chk[tid] += b; }
        __syncthreads();
    }
    if (tid < C_CLS) {
        int off = s_off[tid] - cnt;   // exclusive prefix of counts
        int cb  = s_chk[tid] - nch;   // exclusive prefix of chunk counts
        s_base[tid] = off;
        s_cur[tid]  = 0;
        for (int j = 0; j < nch; ++j) {
            chunk_cls[cb + j]   = tid;
            chunk_start[cb + j] = off + j * S_CHUNK;
            chunk_len[cb + j]   = min(S_CHUNK, cnt - j * S_CHUNK);
        }
    }
    if (tid == 127) *total_chunks = s_chk[127];
    __syncthreads();
    for (int i = tid; i < B_N; i += 1024) {
        int c = cls[i];
        int p = atomicAdd(&s_cur[c], 1);
        order[s_base[c] + p] = i;
    }
}

// ---------------- main kernel ----------------
// grid: (MAX_CHUNKS, U_DIM/TU, DF), block: 64 threads (1 wave).
// Each block: one chunk (<=8 same-class samples) x 256-wide u-tile x 64-row
// d-slice. W reads disjoint across (y,z). Double-buffered W prefetch.

#define LOADW(B0, B1, B2, B3, d4) do {                                   \
    const float* Wr_ = W + (size_t)(4 * (d4)) * U_DIM;                   \
    B0 = *reinterpret_cast<const float4*>(Wr_);                          \
    B1 = *reinterpret_cast<const float4*>(Wr_ + U_DIM);                  \
    B2 = *reinterpret_cast<const float4*>(Wr_ + 2 * U_DIM);              \
    B3 = *reinterpret_cast<const float4*>(Wr_ + 3 * U_DIM);              \
} while (0)

#define COMP(B0, B1, B2, B3, d4) do {                                    \
    _Pragma("unroll")                                                    \
    for (int s = 0; s < S_CHUNK; ++s) {                                  \
        float4 xv = *reinterpret_cast<const float4*>(&xs[s][4 * (d4)]);  \
        acc[s][0] = fmaf(xv.x, B0.x, acc[s][0]);                         \
        acc[s][0] = fmaf(xv.y, B1.x, acc[s][0]);                         \
        acc[s][0] = fmaf(xv.z, B2.x, acc[s][0]);                         \
        acc[s][0] = fmaf(xv.w, B3.x, acc[s][0]);                         \
        acc[s][1] = fmaf(xv.x, B0.y, acc[s][1]);                         \
        acc[s][1] = fmaf(xv.y, B1.y, acc[s][1]);                         \
        acc[s][1] = fmaf(xv.z, B2.y, acc[s][1]);                         \
        acc[s][1] = fmaf(xv.w, B3.y, acc[s][1]);                         \
        acc[s][2] = fmaf(xv.x, B0.z, acc[s][2]);                         \
        acc[s][2] = fmaf(xv.y, B1.z, acc[s][2]);                         \
        acc[s][2] = fmaf(xv.z, B2.z, acc[s][2]);                         \
        acc[s][2] = fmaf(xv.w, B3.z, acc[s][2]);                         \
        acc[s][3] = fmaf(xv.x, B0.w, acc[s][3]);                         \
        acc[s][3] = fmaf(xv.y, B1.w, acc[s][3]);                         \
        acc[s][3] = fmaf(xv.z, B2.w, acc[s][3]);                         \
        acc[s][3] = fmaf(xv.w, B3.w, acc[s][3]);                         \
    }                                                                    \
} while (0)

__launch_bounds__(64)
__global__ void k_main(const float* __restrict__ x, const float* __restrict__ kern,
                       const float* __restrict__ bias, const int* __restrict__ order,
                       const int* __restrict__ total_chunks,
                       const int* __restrict__ chunk_cls,
                       const int* __restrict__ chunk_start,
                       const int* __restrict__ chunk_len,
                       float* __restrict__ out) {
    int chunk = blockIdx.x;
    if (chunk >= *total_chunks) return;
    int tid   = threadIdx.x;
    int c     = chunk_cls[chunk];
    int start = chunk_start[chunk];
    int len   = chunk_len[chunk];
    int d0    = blockIdx.z * DS;    // this block's d-slice [d0, d0+64)

    __shared__ int   sidx[S_CHUNK];
    __shared__ float xs[S_CHUNK][DS];   // 8 x 64 floats = 2 KB

    if (tid < S_CHUNK) sidx[tid] = (tid < len) ? order[start + tid] : -1;
    __syncthreads();

    // stage x[:, d0:d0+64]: 8 rows * 16 float4 = 128 loads / 64 threads
    #pragma unroll
    for (int i = tid; i < S_CHUNK * (DS / 4); i += 64) {
        int s = i >> 4;     // /16
        int f = i & 15;
        int b = sidx[s];
        float4 v = make_float4(0.f, 0.f, 0.f, 0.f);
        if (b >= 0) v = reinterpret_cast<const float4*>(x)[b * (D_DIM / 4) + (d0 / 4) + f];
        reinterpret_cast<float4*>(xs[s])[f] = v;
    }
    __syncthreads();

    int u0 = blockIdx.y * TU + tid * 4;
    const float* W = kern + (size_t)c * (D_DIM * U_DIM) + (size_t)d0 * U_DIM + u0;

    float acc[S_CHUNK][4];
    #pragma unroll
    for (int s = 0; s < S_CHUNK; ++s) {
        acc[s][0] = 0.f; acc[s][1] = 0.f; acc[s][2] = 0.f; acc[s][3] = 0.f;
    }

    float4 wa0, wa1, wa2, wa3, wb0, wb1, wb2, wb3;

    // 16 d4-steps, software-pipelined 2-deep (4 float4 loads in flight)
    LOADW(wa0, wa1, wa2, wa3, 0);
    #pragma unroll 1
    for (int i = 0; i < 7; ++i) {
        LOADW(wb0, wb1, wb2, wb3, 2 * i + 1);
        COMP (wa0, wa1, wa2, wa3, 2 * i);
        LOADW(wa0, wa1, wa2, wa3, 2 * i + 2);
        COMP (wb0, wb1, wb2, wb3, 2 * i + 1);
    }
    LOADW(wb0, wb1, wb2, wb3, 15);
    COMP (wa0, wa1, wa2, wa3, 14);
    COMP (wb0, wb1, wb2, wb3, 15);

    // bias folded into the z==0 partial; f32 atomicAdd into zeroed out
    float4 bb = make_float4(0.f, 0.f, 0.f, 0.f);
    if (blockIdx.z == 0) bb = *reinterpret_cast<const float4*>(bias + c * U_DIM + u0);

    #pragma unroll
    for (int s = 0; s < S_CHUNK; ++s) {   // static indices into acc
        if (s < len) {
            int b = sidx[s];
            float* o = out + (size_t)b * U_DIM + u0;
            atomicAdd(o + 0, acc[s][0] + bb.x);
            atomicAdd(o + 1, acc[s][1] + bb.y);
            atomicAdd(o + 2, acc[s][2] + bb.z);
            atomicAdd(o + 3, acc[s][3] + bb.w);
        }
    }
}

// ---------------- launch ----------------

extern "C" void kernel_launch(void* const* d_in, const int* in_sizes, int n_in,
                              void* d_out, int out_size, void* d_ws, size_t ws_size,
                              hipStream_t stream) {
    const float* x    = (const float*)d_in[0];
    const int*   cls  = (const int*)d_in[1];
    const float* kern = (const float*)d_in[2];
    const float* bias = (const float*)d_in[3];
    float*       out  = (float*)d_out;

    int* ws           = (int*)d_ws;
    int* order        = ws;          // 2048
    int* total_chunks = ws + 2048;   // 1
    int* chunk_cls    = ws + 2112;   // 360
    int* chunk_start  = ws + 2472;   // 360
    int* chunk_len    = ws + 2832;   // 360

    hipMemsetAsync(d_out, 0, (size_t)out_size * sizeof(float), stream);
    hipLaunchKernelGGL(k_sort, dim3(1), dim3(1024), 0, stream,
                       cls, order, total_chunks, chunk_cls, chunk_start, chunk_len);
    hipLaunchKernelGGL(k_main, dim3(MAX_CHUNKS, U_DIM / TU, DF), dim3(64), 0, stream,
                       x, kern, bias, order, total_chunks, chunk_cls, chunk_start, chunk_len, out);
}

// Round 4
// 42.048 us; speedup vs baseline: 3.6309x; 3.6309x over previous
//
#include <hip/hip_runtime.h>

// ConditionalDense: out[b,u] = sum_d x[b,d]*kernel[cls[b],d,u] + bias[cls[b],u]
// B=2048, D=512, U=512, C=100, all float32.
// R3: counting sort (S=16) + grouped-GEMM blocks: (chunk x 256-u-tile),
// 256 thr, full D in-block (no atomics). W staged via global_load_lds
// double-buffer with counted vmcnt + raw barriers. XCD-swizzled grid.

constexpr int C_CLS   = 100;
constexpr int B_N     = 2048;
constexpr int D_DIM   = 512;
constexpr int U_DIM   = 512;
constexpr int S_CHUNK = 16;     // samples per chunk
constexpr int MAX_CHUNKS = 228; // >= worst case (2048+100*15)/16 = 221
constexpr int TU      = 256;    // u-columns per block
constexpr int PROWS   = 16;     // d-rows per staged W piece (16 KB)
constexpr int PIECES  = D_DIM / PROWS;   // 32
constexpr int NWG     = 2 * MAX_CHUNKS;  // 456, divisible by 8 (XCD swizzle)

// ---------------- fused sort kernel (single block, 1024 threads) ----------------

__global__ void k_sort(const int* __restrict__ cls, int* __restrict__ order,
                       int* __restrict__ total_chunks, int* __restrict__ chunk_cls,
                       int* __restrict__ chunk_start, int* __restrict__ chunk_len) {
    __shared__ int s_cnt[128], s_off[128], s_chk[128], s_cur[128], s_base[128];
    int tid = threadIdx.x;
    if (tid < 128) s_cnt[tid] = 0;
    __syncthreads();
    for (int i = tid; i < B_N; i += 1024) atomicAdd(&s_cnt[cls[i]], 1);
    __syncthreads();
    int cnt = 0, nch = 0;
    if (tid < 128) {
        cnt = (tid < C_CLS) ? s_cnt[tid] : 0;
        nch = (cnt + S_CHUNK - 1) / S_CHUNK;
        s_off[tid] = cnt; s_chk[tid] = nch;
    }
    __syncthreads();
    for (int st = 1; st < 128; st <<= 1) {   // Hillis-Steele inclusive scan
        int a = 0, b = 0;
        if (tid >= st && tid < 128) { a = s_off[tid - st]; b = s_chk[tid - st]; }
        __syncthreads();
        if (tid < 128) { s_off[tid] += a; s_chk[tid] += b; }
        __syncthreads();
    }
    if (tid < C_CLS) {
        int off = s_off[tid] - cnt;   // exclusive prefix of counts
        int cb  = s_chk[tid] - nch;   // exclusive prefix of chunk counts
        s_base[tid] = off;
        s_cur[tid]  = 0;
        for (int j = 0; j < nch; ++j) {
            chunk_cls[cb + j]   = tid;
            chunk_start[cb + j] = off + j * S_CHUNK;
            chunk_len[cb + j]   = min(S_CHUNK, cnt - j * S_CHUNK);
        }
    }
    if (tid == 127) *total_chunks = s_chk[127];
    __syncthreads();
    for (int i = tid; i < B_N; i += 1024) {
        int c = cls[i];
        int p = atomicAdd(&s_cur[c], 1);
        order[s_base[c] + p] = i;
    }
}

// ---------------- main kernel ----------------
// Wave wv owns samples 4wv..4wv+3; thread lane owns u = u0 + lane*4.
// wbuf: double-buffered 16x256 f32 W piece, filled by global_load_lds
// (wave-uniform LDS base + lane*16, linear — required by HW).

#define ISSUE(pi) do {                                                        \
    const int q_ = (pi) & 1; const int db_ = (pi) * PROWS;                    \
    _Pragma("unroll")                                                         \
    for (int j_ = 0; j_ < 4; ++j_) {                                          \
        const int r_ = wv * 4 + j_;                                           \
        const float* gp_ = Wg + (size_t)(db_ + r_) * U_DIM + lane * 4;        \
        __builtin_amdgcn_global_load_lds(                                     \
            (const __attribute__((address_space(1))) void*)gp_,               \
            (__attribute__((address_space(3))) void*)&wbuf[q_][r_][0],        \
            16, 0, 0);                                                        \
    }                                                                         \
} while (0)

#define COMPUTE(pi) do {                                                      \
    const int q_ = (pi) & 1; const int dbase_ = (pi) * PROWS;                 \
    _Pragma("unroll")                                                         \
    for (int g4 = 0; g4 < PROWS / 4; ++g4) {                                  \
        float4 w0 = *reinterpret_cast<const float4*>(&wbuf[q_][4*g4+0][lane*4]); \
        float4 w1 = *reinterpret_cast<const float4*>(&wbuf[q_][4*g4+1][lane*4]); \
        float4 w2 = *reinterpret_cast<const float4*>(&wbuf[q_][4*g4+2][lane*4]); \
        float4 w3 = *reinterpret_cast<const float4*>(&wbuf[q_][4*g4+3][lane*4]); \
        _Pragma("unroll")                                                     \
        for (int k = 0; k < 4; ++k) {                                         \
            float4 xq = *reinterpret_cast<const float4*>(&xs[4*wv + k][dbase_ + 4*g4]); \
            acc[k].x = fmaf(xq.x, w0.x, acc[k].x);                            \
            acc[k].x = fmaf(xq.y, w1.x, acc[k].x);                            \
            acc[k].x = fmaf(xq.z, w2.x, acc[k].x);                            \
            acc[k].x = fmaf(xq.w, w3.x, acc[k].x);                            \
            acc[k].y = fmaf(xq.x, w0.y, acc[k].y);                            \
            acc[k].y = fmaf(xq.y, w1.y, acc[k].y);                            \
            acc[k].y = fmaf(xq.z, w2.y, acc[k].y);                            \
            acc[k].y = fmaf(xq.w, w3.y, acc[k].y);                            \
            acc[k].z = fmaf(xq.x, w0.z, acc[k].z);                            \
            acc[k].z = fmaf(xq.y, w1.z, acc[k].z);                            \
            acc[k].z = fmaf(xq.z, w2.z, acc[k].z);                            \
            acc[k].z = fmaf(xq.w, w3.z, acc[k].z);                            \
            acc[k].w = fmaf(xq.x, w0.w, acc[k].w);                            \
            acc[k].w = fmaf(xq.y, w1.w, acc[k].w);                            \
            acc[k].w = fmaf(xq.z, w2.w, acc[k].w);                            \
            acc[k].w = fmaf(xq.w, w3.w, acc[k].w);                            \
        }                                                                     \
    }                                                                         \
} while (0)

__launch_bounds__(256, 2)
__global__ void k_main(const float* __restrict__ x, const float* __restrict__ kern,
                       const float* __restrict__ bias, const int* __restrict__ order,
                       const int* __restrict__ total_chunks,
                       const int* __restrict__ chunk_cls,
                       const int* __restrict__ chunk_start,
                       const int* __restrict__ chunk_len,
                       float* __restrict__ out) {
    // XCD-aware swizzle (bijective: NWG % 8 == 0): consecutive work ids
    // (same chunk's two u-tiles, same class's chunks) land on one XCD.
    int lin   = blockIdx.x;
    int g     = (lin & 7) * (NWG / 8) + (lin >> 3);
    int chunk = g >> 1;
    int ytile = g & 1;
    if (chunk >= *total_chunks) return;   // block-uniform exit (before barriers)

    int tid  = threadIdx.x;
    int lane = tid & 63;
    int wv   = tid >> 6;

    int c     = chunk_cls[chunk];
    int start = chunk_start[chunk];
    int len   = chunk_len[chunk];
    int u0    = ytile * TU;

    __shared__ float wbuf[2][PROWS][TU];   // 32 KB
    __shared__ float xs[S_CHUNK][D_DIM];   // 32 KB
    __shared__ int   sidx[S_CHUNK];

    const float* Wg = kern + (size_t)c * (D_DIM * U_DIM) + u0;

    // ---- prologue: issue W pieces 0,1; stage sidx + x; one full drain ----
    ISSUE(0);
    ISSUE(1);
    if (tid < S_CHUNK) sidx[tid] = (tid < len) ? order[start + tid] : -1;
    asm volatile("s_waitcnt lgkmcnt(0)" ::: "memory");
    __builtin_amdgcn_s_barrier();          // sidx visible

    float4 xv[8];
    #pragma unroll
    for (int j = 0; j < 8; ++j) {          // 16 rows x 128 float4 / 256 thr
        int i = tid + 256 * j;
        int s = i >> 7, f = i & 127;
        int b = sidx[s];
        xv[j] = make_float4(0.f, 0.f, 0.f, 0.f);
        if (b >= 0) xv[j] = reinterpret_cast<const float4*>(x)[b * (D_DIM / 4) + f];
    }
    asm volatile("s_waitcnt vmcnt(0)" ::: "memory");   // x loaded (+ pieces 0,1 landed)
    #pragma unroll
    for (int j = 0; j < 8; ++j) {
        int i = tid + 256 * j;
        int s = i >> 7, f = i & 127;
        reinterpret_cast<float4*>(&xs[s][0])[f] = xv[j];
    }
    asm volatile("s_waitcnt lgkmcnt(0)" ::: "memory");
    __builtin_amdgcn_s_barrier();          // xs visible; pipeline primed

    float4 acc[4];
    #pragma unroll
    for (int k = 0; k < 4; ++k) acc[k] = make_float4(0.f, 0.f, 0.f, 0.f);

    // ---- main pipelined loop: compute(i) while piece i+1 is in flight ----
    #pragma unroll 1
    for (int i = 0; i < PIECES; ++i) {
        if (i > 0) {
            if (i + 1 < PIECES) asm volatile("s_waitcnt vmcnt(4)" ::: "memory");
            else                asm volatile("s_waitcnt vmcnt(0)" ::: "memory");
        }
        __builtin_amdgcn_s_barrier();      // all waves' rows of piece i in LDS
        COMPUTE(i);
        asm volatile("" ::: "memory");     // keep ds_reads above barrier2
        __builtin_amdgcn_s_barrier();      // all waves done reading buf[i&1]
        if (i + 2 < PIECES) ISSUE(i + 2);  // safe: overwrites buf[i&1]
    }

    // ---- epilogue: direct stores, one writer per output element ----
    float4 bb = *reinterpret_cast<const float4*>(&bias[c * U_DIM + u0 + lane * 4]);
    #pragma unroll
    for (int k = 0; k < 4; ++k) {
        int b = sidx[4 * wv + k];
        if (b >= 0) {
            float4 o = make_float4(acc[k].x + bb.x, acc[k].y + bb.y,
                                   acc[k].z + bb.z, acc[k].w + bb.w);
            *reinterpret_cast<float4*>(&out[(size_t)b * U_DIM + u0 + lane * 4]) = o;
        }
    }
}

// ---------------- launch ----------------

extern "C" void kernel_launch(void* const* d_in, const int* in_sizes, int n_in,
                              void* d_out, int out_size, void* d_ws, size_t ws_size,
                              hipStream_t stream) {
    const float* x    = (const float*)d_in[0];
    const int*   cls  = (const int*)d_in[1];
    const float* kern = (const float*)d_in[2];
    const float* bias = (const float*)d_in[3];
    float*       out  = (float*)d_out;

    int* ws           = (int*)d_ws;
    int* order        = ws;          // 2048
    int* total_chunks = ws + 2048;   // 1
    int* chunk_cls    = ws + 2112;   // 228
    int* chunk_start  = ws + 2368;   // 228
    int* chunk_len    = ws + 2624;   // 228

    hipLaunchKernelGGL(k_sort, dim3(1), dim3(1024), 0, stream,
                       cls, order, total_chunks, chunk_cls, chunk_start, chunk_len);
    hipLaunchKernelGGL(k_main, dim3(NWG), dim3(256), 0, stream,
                       x, kern, bias, order, total_chunks, chunk_cls, chunk_start, chunk_len, out);
}